// Round 4
// baseline (4562.421 us; speedup 1.0000x reference)
//
#include <hip/hip_runtime.h>

#define HID 256
#define TLEN 1024
#define BATCH 128

typedef _Float16 half2_t __attribute__((ext_vector_type(2)));

__device__ __forceinline__ float fexp2(float x) { return __builtin_amdgcn_exp2f(x); }
__device__ __forceinline__ float frcp(float x)  { return __builtin_amdgcn_rcpf(x); }
__device__ __forceinline__ float fast_sigmoid(float x) {
  return frcp(1.0f + fexp2(-1.442695040888963f * x));
}
__device__ __forceinline__ float fast_tanh(float x) {
  float e = fexp2(2.885390081777927f * x);
  return 1.0f - 2.0f * frcp(e + 1.0f);
}
__device__ __forceinline__ float dot2acc(half2_t a, half2_t b, float c) {
  return __builtin_amdgcn_fdot2(a, b, c, false);   // v_dot2_f32_f16
}

#if defined(__has_builtin) && __has_builtin(__builtin_amdgcn_sdot4)
#define SDOT4(a, b, c) __builtin_amdgcn_sdot4((int)(a), (int)(b), (c), false)
#else
__device__ __forceinline__ int SDOT4(int a, int b, int c) {
#pragma unroll
  for (int e = 0; e < 4; ++e)
    c += ((a << (24 - 8 * e)) >> 24) * ((b << (24 - 8 * e)) >> 24);
  return c;
}
#endif

// AGPR parking: values live in AGPRs as outputs of volatile asm -- the
// allocator cannot rematerialize them from memory (opaque asm output), and
// the VGPR-occupancy heuristic doesn't count them against its target.
#define AGPR_WRITE(dst, src) \
  asm volatile("v_accvgpr_write_b32 %0, %1" : "=a"(dst) : "v"(src))
#define AGPR_READ(dst, src) \
  asm volatile("v_accvgpr_read_b32 %0, %1" : "=v"(dst) : "a"(src))

// DPP (VALU pipe). Verified on this HW in earlier rounds.
#define DPP_ADD_F(var, ctrl, rmask)                                            \
  var += __builtin_bit_cast(float, __builtin_amdgcn_update_dpp(                \
      0, __builtin_bit_cast(int, var), (ctrl), (rmask), 0xf, true))
#define DPP_ADD_I(var, ctrl, rmask)                                            \
  var += __builtin_amdgcn_update_dpp(0, (var), (ctrl), (rmask), 0xf, true)

__device__ __forceinline__ float wave_sum63_f(float p) {
  DPP_ADD_F(p, 0x111, 0xf);
  DPP_ADD_F(p, 0x112, 0xf);
  DPP_ADD_F(p, 0x114, 0xf);
  DPP_ADD_F(p, 0x118, 0xf);
  DPP_ADD_F(p, 0x142, 0xa);
  DPP_ADD_F(p, 0x143, 0xc);   // -> lane63 has wave total
  return p;
}
__device__ __forceinline__ int wave_sum63_i(int p) {
  DPP_ADD_I(p, 0x111, 0xf);
  DPP_ADD_I(p, 0x112, 0xf);
  DPP_ADD_I(p, 0x114, 0xf);
  DPP_ADD_I(p, 0x118, 0xf);
  DPP_ADD_I(p, 0x142, 0xa);
  DPP_ADD_I(p, 0x143, 0xc);   // -> lane63 has wave total (exact, int)
  return p;
}

// ---- prep: per-row i8 quant of W_hh (768x256), layout wq[row*16 + c]
// (row-contiguous so persistent thread r loads 16 consecutive uint4);
// plus i8 pack of Wb_h with folded scale so hWb = sdot_total * wbscale.
__global__ void quant_whh(const float* __restrict__ W_hh,
                          const float* __restrict__ Wb_h,
                          uint4* __restrict__ wq,
                          float* __restrict__ scales,
                          unsigned* __restrict__ wbq,
                          float* __restrict__ wbscale) {
  const int r = blockIdx.x * 256 + threadIdx.x;   // 0..1023
  if (r < 768) {
    const float* row = W_hh + (size_t)r * HID;
    float amax = 0.0f;
    for (int k = 0; k < HID; ++k) amax = fmaxf(amax, fabsf(row[k]));
    amax = fmaxf(amax, 1e-20f);
    scales[r] = amax / 127.0f;
    const float inv = 127.0f / amax;
    for (int c = 0; c < 16; ++c) {
      unsigned w[4];
#pragma unroll
      for (int u = 0; u < 4; ++u) {
        unsigned bb = 0;
#pragma unroll
        for (int e = 0; e < 4; ++e) {
          int qv = (int)rintf(row[16 * c + 4 * u + e] * inv);
          bb |= (unsigned)(qv & 0xff) << (8 * e);
        }
        w[u] = bb;
      }
      wq[(size_t)r * 16 + c] = uint4{w[0], w[1], w[2], w[3]};
    }
  } else if (r < 832) {
    // threads 768..831: pack Wb_h word (r-768); amax computed redundantly
    float amax = 0.0f;
    for (int k = 0; k < HID; ++k) amax = fmaxf(amax, fabsf(Wb_h[k]));
    amax = fmaxf(amax, 1e-20f);
    const float inv = 127.0f / amax;
    const int i = r - 768;
    unsigned bb = 0;
#pragma unroll
    for (int e = 0; e < 4; ++e) {
      int qv = (int)rintf(Wb_h[4 * i + e] * inv);
      bb |= (unsigned)(qv & 0xff) << (8 * e);
    }
    wbq[i] = bb;
    if (i == 0) wbscale[0] = (amax / 127.0f) * (1.0f / 127.0f);
  }
}

// R17: gate-split persistent kernel, weights parked in AGPRs. 768 threads
// (12 waves, 3 waves/SIMD). Thread tid owns row tid of the 768x256 matvec.
// R15/R16 failure: "+v" pins could not stop the allocator from keeping the
// 16 uint4 weight loads inside the loop (VGPR=76, 196KB/block/step re-read
// from L2 ~= the whole per-step budget). Fix: explicit AGPR parking via
// "a"-constraint asm (v_accvgpr_write once; volatile v_accvgpr_read 4 dwords
// at a time in the burst). Volatile reads so LICM cannot hoist all 64 out of
// the loop. ~76 VGPR + 64 AGPR ~= 140 unified regs -> still 3 waves/SIMD.
__global__
__attribute__((amdgpu_flat_work_group_size(768, 768)))
__attribute__((amdgpu_waves_per_eu(3, 3)))
void momgru_persistent(const float* __restrict__ x,
                       const float* __restrict__ W_ih,
                       const float* __restrict__ b_ih,
                       const float* __restrict__ b_hh,
                       const float* __restrict__ Wb_x,
                       const float* __restrict__ b_beta,
                       const float* __restrict__ s_ptr,
                       const float* __restrict__ W_head,
                       const float* __restrict__ b_head,
                       const uint4* __restrict__ wq,
                       const float* __restrict__ scales,
                       const unsigned* __restrict__ wbq,
                       const float* __restrict__ wbscale,
                       float* __restrict__ out)  // [0,128) head, [128,128+B*T) betas
{
  const int b    = blockIdx.x;
  const int tid  = threadIdx.x;   // row r of [768 x 256]
  const int lane = tid & 63;
  const int wv   = tid >> 6;      // 0..11
  const int g    = tid >> 8;      // 0=r,1=z,2=n (wave-uniform)
  const int d    = tid & 255;     // hidden dim

  __shared__ __align__(16) unsigned hq[64];   // h_t as i8 (single buffer)
  __shared__ float rz2[256][2];               // r,z gate values, paired per dim
  __shared__ float headred[4];

  // ---- weights: 16 uint4 per row -> parked in 64 AGPRs ----
  const uint4* wqt = wq + (size_t)tid * 16;
  int wa[64];
  {
    uint4 wtmp[16];
#pragma unroll
    for (int j = 0; j < 16; ++j) wtmp[j] = wqt[j];
#pragma unroll
    for (int j = 0; j < 16; ++j) {
      AGPR_WRITE(wa[4 * j + 0], (int)wtmp[j].x);
      AGPR_WRITE(wa[4 * j + 1], (int)wtmp[j].y);
      AGPR_WRITE(wa[4 * j + 2], (int)wtmp[j].z);
      AGPR_WRITE(wa[4 * j + 3], (int)wtmp[j].w);
    }
  }

  // ---- per-thread constants (s pre-folded into input projection) ----
  const float sv = s_ptr[0];
  const half2_t wih2 = half2_t{(_Float16)(sv * W_ih[2 * tid]),
                               (_Float16)(sv * W_ih[2 * tid + 1])};
  const float bih = sv * b_ih[tid];
  const float bhh = b_hh[tid];
  const float sc  = scales[tid] * (1.0f / 127.0f);
  const half2_t wbx2 = half2_t{(_Float16)Wb_x[0], (_Float16)Wb_x[1]};  // uniform
  const float bbeta = b_beta[0];
  const unsigned wbq_l = wbq[lane];       // Wb_h i8, dims 4*lane..4*lane+3
  const float wbsc = wbscale[0];          // folded (amax/127)*(1/127)

  // ---- init ----
  if (tid < 64) hq[tid] = 0u;
  float v = 0.0f, h_old = 0.0f;
  float* betas = out + BATCH;
  const float2* xg2 = reinterpret_cast<const float2*>(x + (size_t)b * TLEN * 2);
  float2 xv = xg2[0];
  __syncthreads();

  for (int t = 0; t < TLEN; ++t) {
    // ---- phase 1a: per-wave hWb from h_{t-1} i8 words (hides under burst) --
    const unsigned hw_l = reinterpret_cast<const unsigned*>(hq)[lane];
    int hwb_i = SDOT4(hw_l, wbq_l, 0);
    hwb_i = wave_sum63_i(hwb_i);

    // ---- phase 1b: i8 matvec burst, 4 accumulators, AGPR unpark 4-at-a-time
    const int4* hb = reinterpret_cast<const int4*>(hq);   // 16 x int4, uniform
    int a0 = 0, a1 = 0, a2 = 0, a3 = 0;
#pragma unroll
    for (int c = 0; c < 4; ++c) {
#pragma unroll
      for (int u = 0; u < 4; ++u) {
        const int4 hh = hb[4 * c + u];
        int w0, w1, w2, w3;
        AGPR_READ(w0, wa[16 * c + 4 * u + 0]);
        AGPR_READ(w1, wa[16 * c + 4 * u + 1]);
        AGPR_READ(w2, wa[16 * c + 4 * u + 2]);
        AGPR_READ(w3, wa[16 * c + 4 * u + 3]);
        a0 = SDOT4(hh.x, w0, a0);
        a1 = SDOT4(hh.y, w1, a1);
        a2 = SDOT4(hh.z, w2, a2);
        a3 = SDOT4(hh.w, w3, a3);
      }
    }
    const int a = (a0 + a1) + (a2 + a3);
    const float ga = fmaf((float)a, sc, bhh);       // hidden projection, this row

    // ---- phase 1c: beta + momentum + r/z sigma ----
    const float hWb = (float)__builtin_amdgcn_readlane(hwb_i, 63) * wbsc;
    const half2_t x2 = half2_t{(_Float16)xv.x, (_Float16)xv.y};
    xv = xg2[(t + 1 < TLEN) ? t + 1 : t];           // prefetch next x
    const float beta = fast_sigmoid(dot2acc(x2, wbx2, hWb + bbeta));
    v = beta * v + dot2acc(x2, wih2, bih);
    if (tid == 0) betas[(size_t)b * TLEN + t] = beta;

    if (g < 2) rz2[d][g] = fast_sigmoid(v + ga);    // r,z -> LDS
    __syncthreads();

    // ---- phase 2 (n-waves only): n, h', quantize ----
    if (g == 2) {
      const float2 rzv = *reinterpret_cast<const float2*>(&rz2[d][0]);  // b64
      const float n_ = fast_tanh(fmaf(rzv.x, ga, v));
      h_old = fmaf(rzv.y, h_old - n_, n_);          // (1-z)n + z h
      const int q = (int)rintf(h_old * 127.0f);
      reinterpret_cast<unsigned char*>(hq)[d] = (unsigned char)(q & 0xff);
    }
    __syncthreads();
  }

  // ---- head (h_T lives in the n-waves) ----
  if (g == 2) {
    float hp = h_old * W_head[d];
    hp = wave_sum63_f(hp);
    if (lane == 63) headred[wv - 8] = hp;
  }
  __syncthreads();
  if (tid == 0)
    out[b] = ((headred[0] + headred[1]) + (headred[2] + headred[3])) + b_head[0];
}

extern "C" void kernel_launch(void* const* d_in, const int* in_sizes, int n_in,
                              void* d_out, int out_size, void* d_ws, size_t ws_size,
                              hipStream_t stream) {
  const float* x      = (const float*)d_in[0];
  const float* W_ih   = (const float*)d_in[1];
  const float* W_hh   = (const float*)d_in[2];
  const float* b_ih   = (const float*)d_in[3];
  const float* b_hh   = (const float*)d_in[4];
  const float* Wb_x   = (const float*)d_in[5];
  const float* Wb_h   = (const float*)d_in[6];
  const float* b_beta = (const float*)d_in[7];
  const float* s      = (const float*)d_in[8];
  const float* W_head = (const float*)d_in[9];
  const float* b_head = (const float*)d_in[10];
  float* out = (float*)d_out;

  char* wsb = (char*)d_ws;
  uint4*    wq      = (uint4*)wsb;                 // 768*16*16 = 196608 B
  float*    scales  = (float*)(wsb + 196608);      // 768*4 = 3072 B
  unsigned* wbq     = (unsigned*)(wsb + 199680);   // 64*4 = 256 B
  float*    wbscale = (float*)(wsb + 199936);      // 4 B

  quant_whh<<<dim3(4), dim3(256), 0, stream>>>(W_hh, Wb_h, wq, scales, wbq, wbscale);
  momgru_persistent<<<dim3(BATCH), dim3(768), 0, stream>>>(
      x, W_ih, b_ih, b_hh, Wb_x, b_beta, s, W_head, b_head,
      (const uint4*)wq, (const float*)scales, (const unsigned*)wbq,
      (const float*)wbscale, out);
}

// Round 5
// 1250.776 us; speedup vs baseline: 3.6477x; 3.6477x over previous
//
#include <hip/hip_runtime.h>

#define HID 256
#define TLEN 1024
#define BATCH 128

typedef _Float16 half2_t __attribute__((ext_vector_type(2)));

__device__ __forceinline__ float fexp2(float x) { return __builtin_amdgcn_exp2f(x); }
__device__ __forceinline__ float frcp(float x)  { return __builtin_amdgcn_rcpf(x); }
__device__ __forceinline__ float fast_sigmoid(float x) {
  return frcp(1.0f + fexp2(-1.442695040888963f * x));
}
__device__ __forceinline__ float fast_tanh(float x) {
  float e = fexp2(2.885390081777927f * x);
  return 1.0f - 2.0f * frcp(e + 1.0f);
}
__device__ __forceinline__ float dot2acc(half2_t a, half2_t b, float c) {
  return __builtin_amdgcn_fdot2(a, b, c, false);   // v_dot2_f32_f16
}

#if defined(__has_builtin) && __has_builtin(__builtin_amdgcn_sdot4)
#define SDOT4(a, b, c) __builtin_amdgcn_sdot4((int)(a), (int)(b), (c), false)
#else
__device__ __forceinline__ int SDOT4(int a, int b, int c) {
#pragma unroll
  for (int e = 0; e < 4; ++e)
    c += ((a << (24 - 8 * e)) >> 24) * ((b << (24 - 8 * e)) >> 24);
  return c;
}
#endif

// DPP (VALU pipe). Verified on this HW R6-R12.
#define DPP_ADD_F(var, ctrl, rmask)                                            \
  var += __builtin_bit_cast(float, __builtin_amdgcn_update_dpp(                \
      0, __builtin_bit_cast(int, var), (ctrl), (rmask), 0xf, true))
#define DPP_ADD_I(var, ctrl, rmask)                                            \
  var += __builtin_amdgcn_update_dpp(0, (var), (ctrl), (rmask), 0xf, true)

__device__ __forceinline__ float wave_sum63_f(float p) {
  DPP_ADD_F(p, 0x111, 0xf);
  DPP_ADD_F(p, 0x112, 0xf);
  DPP_ADD_F(p, 0x114, 0xf);
  DPP_ADD_F(p, 0x118, 0xf);
  DPP_ADD_F(p, 0x142, 0xa);
  DPP_ADD_F(p, 0x143, 0xc);   // -> lane63 has wave total
  return p;
}
__device__ __forceinline__ int wave_sum63_i(int p) {
  DPP_ADD_I(p, 0x111, 0xf);
  DPP_ADD_I(p, 0x112, 0xf);
  DPP_ADD_I(p, 0x114, 0xf);
  DPP_ADD_I(p, 0x118, 0xf);
  DPP_ADD_I(p, 0x142, 0xa);
  DPP_ADD_I(p, 0x143, 0xc);   // -> lane63 has wave total (exact, int)
  return p;
}

// ---- prep: per-row i8 quant of W_hh (768x256) for one-thread-per-dim
// (wq[d*48 + g*16 + c]); plus i8 pack of Wb_h (word i = dims 4i..4i+3) with
// folded scale (amax/127 * 1/127) so hWb = sdot_total * wbscale.
__global__ void quant_whh(const float* __restrict__ W_hh,
                          const float* __restrict__ Wb_h,
                          uint4* __restrict__ wq,
                          float* __restrict__ scales,
                          unsigned* __restrict__ wbq,
                          float* __restrict__ wbscale) {
  const int r = blockIdx.x * 256 + threadIdx.x;   // 0..1023
  if (r < 768) {
    const float* row = W_hh + (size_t)r * HID;
    float amax = 0.0f;
    for (int k = 0; k < HID; ++k) amax = fmaxf(amax, fabsf(row[k]));
    amax = fmaxf(amax, 1e-20f);
    scales[r] = amax / 127.0f;
    const float inv = 127.0f / amax;
    const int g = r >> 8, dd = r & 255;
    for (int c = 0; c < 16; ++c) {
      unsigned w[4];
#pragma unroll
      for (int u = 0; u < 4; ++u) {
        unsigned bb = 0;
#pragma unroll
        for (int e = 0; e < 4; ++e) {
          int qv = (int)rintf(row[16 * c + 4 * u + e] * inv);
          bb |= (unsigned)(qv & 0xff) << (8 * e);
        }
        w[u] = bb;
      }
      wq[(size_t)dd * 48 + g * 16 + c] = uint4{w[0], w[1], w[2], w[3]};
    }
  } else if (r < 832) {
    // threads 768..831: pack Wb_h word (r-768); amax computed redundantly
    float amax = 0.0f;
    for (int k = 0; k < HID; ++k) amax = fmaxf(amax, fabsf(Wb_h[k]));
    amax = fmaxf(amax, 1e-20f);
    const float inv = 127.0f / amax;
    const int i = r - 768;
    unsigned bb = 0;
#pragma unroll
    for (int e = 0; e < 4; ++e) {
      int qv = (int)rintf(Wb_h[4 * i + e] * inv);
      bb |= (unsigned)(qv & 0xff) << (8 * e);
    }
    wbq[i] = bb;
    if (i == 0) wbscale[0] = (amax / 127.0f) * (1.0f / 127.0f);
  }
}

// R18: TWO batch elements per block. 512 threads = 2 independent 256-thread
// sub-groups (sub = tid>>8), each running the proven R12/R13 algorithm on its
// own chain; they share only the one __syncthreads per step. Each SIMD now
// hosts 2 waves working on DIFFERENT chains -> mutual latency hiding between
// barriers (R14-R17 lesson: same-chain extra waves don't help, they all wait
// at the same barrier; independence is what hides the ~70% stall time).
// Register plan: identical per-thread footprint to R12 (132 arch + ~120
// auto-parked AGPR = ~252 unified) at waves_per_eu(2,2), budget 256/wave.
__global__
__attribute__((amdgpu_flat_work_group_size(512, 512)))
__attribute__((amdgpu_waves_per_eu(2, 2)))
void momgru_persistent(const float* __restrict__ x,
                       const float* __restrict__ W_ih,
                       const float* __restrict__ b_ih,
                       const float* __restrict__ b_hh,
                       const float* __restrict__ Wb_x,
                       const float* __restrict__ b_beta,
                       const float* __restrict__ s_ptr,
                       const float* __restrict__ W_head,
                       const float* __restrict__ b_head,
                       const uint4* __restrict__ wq,
                       const float* __restrict__ scales,
                       const unsigned* __restrict__ wbq,
                       const float* __restrict__ wbscale,
                       float* __restrict__ out)  // [0,128) head, [128,128+B*T) betas
{
  const int tid  = threadIdx.x;
  const int sub  = tid >> 8;          // 0 or 1: which batch element
  const int stid = tid & 255;         // dim d within the sub-group
  const int lane = tid & 63;
  const int wv   = tid >> 6;          // 0..7
  const int b    = blockIdx.x * 2 + sub;

  __shared__ __align__(16) unsigned hq[2][2][64];  // [sub][buf]: h as i8
  __shared__ float red[8];                         // head reduce (per wave)

  // ---- weights: 48 uint4 (arch regs + auto AGPR-parked overflow) ----
  const uint4* wqt = wq + (size_t)stid * 48;
  uint4 wr[16], wz[16], wn[16];
#pragma unroll
  for (int j = 0; j < 16; ++j) wr[j] = wqt[j];
#pragma unroll
  for (int j = 0; j < 16; ++j) wz[j] = wqt[16 + j];
#pragma unroll
  for (int j = 0; j < 16; ++j) wn[j] = wqt[32 + j];

  // ---- per-thread constants (s pre-folded into input projection) ----
  const float sv = s_ptr[0];
  const half2_t wih_r = half2_t{(_Float16)(sv * W_ih[2 * stid]),             (_Float16)(sv * W_ih[2 * stid + 1])};
  const half2_t wih_z = half2_t{(_Float16)(sv * W_ih[2 * (HID + stid)]),     (_Float16)(sv * W_ih[2 * (HID + stid) + 1])};
  const half2_t wih_n = half2_t{(_Float16)(sv * W_ih[2 * (2 * HID + stid)]), (_Float16)(sv * W_ih[2 * (2 * HID + stid) + 1])};
  const float bih_r = sv * b_ih[stid], bih_z = sv * b_ih[HID + stid], bih_n = sv * b_ih[2 * HID + stid];
  const float bhh_r = b_hh[stid], bhh_z = b_hh[HID + stid], bhh_n = b_hh[2 * HID + stid];
  const float sc_r = scales[stid] * (1.0f / 127.0f);
  const float sc_z = scales[HID + stid] * (1.0f / 127.0f);
  const float sc_n = scales[2 * HID + stid] * (1.0f / 127.0f);
  const half2_t wbx2 = half2_t{(_Float16)Wb_x[0], (_Float16)Wb_x[1]};  // uniform -> SGPR
  const float bbeta = b_beta[0];
  const unsigned wbq_l = wbq[lane];       // Wb_h i8, dims 4*lane..4*lane+3
  const float wbsc = wbscale[0];          // folded (amax/127)*(1/127)

  // ---- init ----
  if (tid < 256) reinterpret_cast<unsigned*>(hq)[tid] = 0u;
  if (tid < 8) red[tid] = 0.0f;
  float h_old = 0.0f, vr = 0.0f, vz = 0.0f, vn = 0.0f;
  float* betas = out + BATCH;
  const float2* xg2 = reinterpret_cast<const float2*>(x + (size_t)b * TLEN * 2);
  float2 xv = xg2[0];
  __syncthreads();

  int cur = 0;
  for (int t = 0; t < TLEN; ++t) {
    // ---- A) per-wave hWb from this sub's h_{t-1} i8 words ----
    const unsigned hw_l = reinterpret_cast<const unsigned*>(hq[sub][cur])[lane];
    int hwb_i = SDOT4(hw_l, wbq_l, 0);
    hwb_i = wave_sum63_i(hwb_i);

    // ---- B) full-k i8 matvec burst, 6 accumulators ----
    int ar0 = 0, az0 = 0, an0 = 0, ar1 = 0, az1 = 0, an1 = 0;
    const int4* hb = reinterpret_cast<const int4*>(hq[sub][cur]);   // 16 x int4
#pragma unroll
    for (int c = 0; c < 8; ++c) {
      const int4 h0 = hb[2 * c];
      const int4 h1 = hb[2 * c + 1];
      ar0 = SDOT4(h0.x, wr[2 * c].x, ar0);
      az0 = SDOT4(h0.x, wz[2 * c].x, az0);
      an0 = SDOT4(h0.x, wn[2 * c].x, an0);
      ar1 = SDOT4(h1.x, wr[2 * c + 1].x, ar1);
      az1 = SDOT4(h1.x, wz[2 * c + 1].x, az1);
      an1 = SDOT4(h1.x, wn[2 * c + 1].x, an1);
      ar0 = SDOT4(h0.y, wr[2 * c].y, ar0);
      az0 = SDOT4(h0.y, wz[2 * c].y, az0);
      an0 = SDOT4(h0.y, wn[2 * c].y, an0);
      ar1 = SDOT4(h1.y, wr[2 * c + 1].y, ar1);
      az1 = SDOT4(h1.y, wz[2 * c + 1].y, az1);
      an1 = SDOT4(h1.y, wn[2 * c + 1].y, an1);
      ar0 = SDOT4(h0.z, wr[2 * c].z, ar0);
      az0 = SDOT4(h0.z, wz[2 * c].z, az0);
      an0 = SDOT4(h0.z, wn[2 * c].z, an0);
      ar1 = SDOT4(h1.z, wr[2 * c + 1].z, ar1);
      az1 = SDOT4(h1.z, wz[2 * c + 1].z, az1);
      an1 = SDOT4(h1.z, wn[2 * c + 1].z, an1);
      ar0 = SDOT4(h0.w, wr[2 * c].w, ar0);
      az0 = SDOT4(h0.w, wz[2 * c].w, az0);
      an0 = SDOT4(h0.w, wn[2 * c].w, an0);
      ar1 = SDOT4(h1.w, wr[2 * c + 1].w, ar1);
      az1 = SDOT4(h1.w, wz[2 * c + 1].w, az1);
      an1 = SDOT4(h1.w, wn[2 * c + 1].w, an1);
    }
    const int ar = ar0 + ar1, az = az0 + az1, an = an0 + an1;

    // ---- C) beta + momentum + gates ----
    const float hWb = (float)__builtin_amdgcn_readlane(hwb_i, 63) * wbsc;
    const half2_t x2 = half2_t{(_Float16)xv.x, (_Float16)xv.y};
    xv = xg2[(t + 1 < TLEN) ? t + 1 : t];
    const float beta = fast_sigmoid(dot2acc(x2, wbx2, hWb + bbeta));
    vr = beta * vr + dot2acc(x2, wih_r, bih_r);
    vz = beta * vz + dot2acc(x2, wih_z, bih_z);
    vn = beta * vn + dot2acc(x2, wih_n, bih_n);

    const float r = fast_sigmoid(vr + (float)ar * sc_r + bhh_r);
    const float z = fast_sigmoid(vz + (float)az * sc_z + bhh_z);
    const float n = fast_tanh(vn + r * ((float)an * sc_n + bhh_n));
    h_old = (1.0f - z) * n + z * h_old;

    // ---- D) quantize h -> i8, one byte store per thread ----
    const int nxt = cur ^ 1;
    const int qb = (int)rintf(h_old * 127.0f);
    reinterpret_cast<unsigned char*>(hq[sub][nxt])[stid] = (unsigned char)(qb & 0xff);

    if (stid == 0) betas[(size_t)b * TLEN + t] = beta;

    __syncthreads();
    cur = nxt;
  }

  // ---- head ----
  float hp = h_old * W_head[stid];
  hp = wave_sum63_f(hp);
  if (lane == 63) red[wv] = hp;
  __syncthreads();
  if (stid == 0)
    out[b] = ((red[4 * sub + 0] + red[4 * sub + 1]) +
              (red[4 * sub + 2] + red[4 * sub + 3])) + b_head[0];
}

extern "C" void kernel_launch(void* const* d_in, const int* in_sizes, int n_in,
                              void* d_out, int out_size, void* d_ws, size_t ws_size,
                              hipStream_t stream) {
  const float* x      = (const float*)d_in[0];
  const float* W_ih   = (const float*)d_in[1];
  const float* W_hh   = (const float*)d_in[2];
  const float* b_ih   = (const float*)d_in[3];
  const float* b_hh   = (const float*)d_in[4];
  const float* Wb_x   = (const float*)d_in[5];
  const float* Wb_h   = (const float*)d_in[6];
  const float* b_beta = (const float*)d_in[7];
  const float* s      = (const float*)d_in[8];
  const float* W_head = (const float*)d_in[9];
  const float* b_head = (const float*)d_in[10];
  float* out = (float*)d_out;

  char* wsb = (char*)d_ws;
  uint4*    wq      = (uint4*)wsb;                 // 256*48*16 = 196608 B
  float*    scales  = (float*)(wsb + 196608);      // 768*4 = 3072 B
  unsigned* wbq     = (unsigned*)(wsb + 199680);   // 64*4 = 256 B
  float*    wbscale = (float*)(wsb + 199936);      // 4 B

  quant_whh<<<dim3(4), dim3(256), 0, stream>>>(W_hh, Wb_h, wq, scales, wbq, wbscale);
  momgru_persistent<<<dim3(BATCH / 2), dim3(512), 0, stream>>>(
      x, W_ih, b_ih, b_hh, Wb_x, b_beta, s, W_head, b_head,
      (const uint4*)wq, (const float*)scales, (const unsigned*)wbq,
      (const float*)wbscale, out);
}

// Round 6
// 889.462 us; speedup vs baseline: 5.1294x; 1.4062x over previous
//
#include <hip/hip_runtime.h>

#define HID 256
#define TLEN 1024
#define BATCH 128

typedef _Float16 half2_t __attribute__((ext_vector_type(2)));

__device__ __forceinline__ float fexp2(float x) { return __builtin_amdgcn_exp2f(x); }
__device__ __forceinline__ float frcp(float x)  { return __builtin_amdgcn_rcpf(x); }
__device__ __forceinline__ float fast_sigmoid(float x) {
  return frcp(1.0f + fexp2(-1.442695040888963f * x));
}
__device__ __forceinline__ float fast_tanh(float x) {
  float e = fexp2(2.885390081777927f * x);
  return 1.0f - 2.0f * frcp(e + 1.0f);
}
__device__ __forceinline__ float dot2acc(half2_t a, half2_t b, float c) {
  return __builtin_amdgcn_fdot2(a, b, c, false);   // v_dot2_f32_f16
}

#if defined(__has_builtin) && __has_builtin(__builtin_amdgcn_sdot4)
#define SDOT4(a, b, c) __builtin_amdgcn_sdot4((int)(a), (int)(b), (c), false)
#else
__device__ __forceinline__ int SDOT4(int a, int b, int c) {
#pragma unroll
  for (int e = 0; e < 4; ++e)
    c += ((a << (24 - 8 * e)) >> 24) * ((b << (24 - 8 * e)) >> 24);
  return c;
}
#endif

// DPP (VALU pipe). Verified on this HW R6-R12.
#define DPP_ADD_F(var, ctrl, rmask)                                            \
  var += __builtin_bit_cast(float, __builtin_amdgcn_update_dpp(                \
      0, __builtin_bit_cast(int, var), (ctrl), (rmask), 0xf, true))
#define DPP_ADD_I(var, ctrl, rmask)                                            \
  var += __builtin_amdgcn_update_dpp(0, (var), (ctrl), (rmask), 0xf, true)

__device__ __forceinline__ float wave_sum63_f(float p) {
  DPP_ADD_F(p, 0x111, 0xf);
  DPP_ADD_F(p, 0x112, 0xf);
  DPP_ADD_F(p, 0x114, 0xf);
  DPP_ADD_F(p, 0x118, 0xf);
  DPP_ADD_F(p, 0x142, 0xa);
  DPP_ADD_F(p, 0x143, 0xc);   // -> lane63 has wave total
  return p;
}
__device__ __forceinline__ int wave_sum63_i(int p) {
  DPP_ADD_I(p, 0x111, 0xf);
  DPP_ADD_I(p, 0x112, 0xf);
  DPP_ADD_I(p, 0x114, 0xf);
  DPP_ADD_I(p, 0x118, 0xf);
  DPP_ADD_I(p, 0x142, 0xa);
  DPP_ADD_I(p, 0x143, 0xc);   // -> lane63 has wave total (exact, int)
  return p;
}

// ---- prep: per-row i8 quant of W_hh (768x256), row-major chunks
// wq[row*16 + c] (c = 16-byte k-chunk); plus i8 pack of Wb_h (word i = dims
// 4i..4i+3) with folded scale (amax/127 * 1/127) so hWb = sdot * wbscale.
__global__ void quant_whh(const float* __restrict__ W_hh,
                          const float* __restrict__ Wb_h,
                          uint4* __restrict__ wq,
                          float* __restrict__ scales,
                          unsigned* __restrict__ wbq,
                          float* __restrict__ wbscale) {
  const int r = blockIdx.x * 256 + threadIdx.x;   // 0..1023
  if (r < 768) {
    const float* row = W_hh + (size_t)r * HID;
    float amax = 0.0f;
    for (int k = 0; k < HID; ++k) amax = fmaxf(amax, fabsf(row[k]));
    amax = fmaxf(amax, 1e-20f);
    scales[r] = amax / 127.0f;
    const float inv = 127.0f / amax;
    for (int c = 0; c < 16; ++c) {
      unsigned w[4];
#pragma unroll
      for (int u = 0; u < 4; ++u) {
        unsigned bb = 0;
#pragma unroll
        for (int e = 0; e < 4; ++e) {
          int qv = (int)rintf(row[16 * c + 4 * u + e] * inv);
          bb |= (unsigned)(qv & 0xff) << (8 * e);
        }
        w[u] = bb;
      }
      wq[(size_t)r * 16 + c] = uint4{w[0], w[1], w[2], w[3]};
    }
  } else if (r < 832) {
    // threads 768..831: pack Wb_h word (r-768); amax computed redundantly
    float amax = 0.0f;
    for (int k = 0; k < HID; ++k) amax = fmaxf(amax, fabsf(Wb_h[k]));
    amax = fmaxf(amax, 1e-20f);
    const float inv = 127.0f / amax;
    const int i = r - 768;
    unsigned bb = 0;
#pragma unroll
    for (int e = 0; e < 4; ++e) {
      int qv = (int)rintf(Wb_h[4 * i + e] * inv);
      bb |= (unsigned)(qv & 0xff) << (8 * e);
    }
    wbq[i] = bb;
    if (i == 0) wbscale[0] = (amax / 127.0f) * (1.0f / 127.0f);
  }
}

// R19: K-SPLIT x2, one chain per block, 128 blocks x 512 threads (8 waves,
// 2/SIMD). Thread (sub=tid>>8, d=tid&255) owns gate-rows {d, 256+d, 512+d}
// over k-half sub: 24 uint4 = 96 weight dwords (fits 256-reg budget at
// waves_per_eu(2,2); R18 verified allocator keeps weights resident there).
// Wave placement puts one lower + one upper wave on each SIMD: independent
// work in every phase -> mutual latency hiding WITHOUT halving the CU count
// (R18's per-CU win at 128 CUs). Upper writes 3 int partials to LDS; lower
// combines + runs the short tail. hWb/beta/v stay in phase 1 under the burst.
__global__
__attribute__((amdgpu_flat_work_group_size(512, 512)))
__attribute__((amdgpu_waves_per_eu(2, 2)))
void momgru_persistent(const float* __restrict__ x,
                       const float* __restrict__ W_ih,
                       const float* __restrict__ b_ih,
                       const float* __restrict__ b_hh,
                       const float* __restrict__ Wb_x,
                       const float* __restrict__ b_beta,
                       const float* __restrict__ s_ptr,
                       const float* __restrict__ W_head,
                       const float* __restrict__ b_head,
                       const uint4* __restrict__ wq,
                       const float* __restrict__ scales,
                       const unsigned* __restrict__ wbq,
                       const float* __restrict__ wbscale,
                       float* __restrict__ out)  // [0,128) head, [128,128+B*T) betas
{
  const int b    = blockIdx.x;
  const int tid  = threadIdx.x;
  const int sub  = tid >> 8;          // 0 = lower k-half (+tail), 1 = upper
  const int d    = tid & 255;         // hidden dim
  const int lane = tid & 63;
  const int wv   = tid >> 6;          // 0..7

  __shared__ __align__(16) unsigned hq[2][64];  // h as i8, double-buffered
  __shared__ int   parts[3 * HID];              // upper-half partial sums
  __shared__ float red[4];                      // head reduce

  // ---- weights: 3 gates x 8 uint4 (own k-half), register-resident ----
  const uint4* wr_p = wq + ((size_t)(0 * HID + d) * 16 + sub * 8);
  const uint4* wz_p = wq + ((size_t)(1 * HID + d) * 16 + sub * 8);
  const uint4* wn_p = wq + ((size_t)(2 * HID + d) * 16 + sub * 8);
  uint4 wr[8], wz[8], wn[8];
#pragma unroll
  for (int j = 0; j < 8; ++j) wr[j] = wr_p[j];
#pragma unroll
  for (int j = 0; j < 8; ++j) wz[j] = wz_p[j];
#pragma unroll
  for (int j = 0; j < 8; ++j) wn[j] = wn_p[j];

  // ---- per-thread constants (s pre-folded into input projection) ----
  const float sv = s_ptr[0];
  const half2_t wih_r = half2_t{(_Float16)(sv * W_ih[2 * d]),             (_Float16)(sv * W_ih[2 * d + 1])};
  const half2_t wih_z = half2_t{(_Float16)(sv * W_ih[2 * (HID + d)]),     (_Float16)(sv * W_ih[2 * (HID + d) + 1])};
  const half2_t wih_n = half2_t{(_Float16)(sv * W_ih[2 * (2 * HID + d)]), (_Float16)(sv * W_ih[2 * (2 * HID + d) + 1])};
  const float bih_r = sv * b_ih[d], bih_z = sv * b_ih[HID + d], bih_n = sv * b_ih[2 * HID + d];
  const float bhh_r = b_hh[d], bhh_z = b_hh[HID + d], bhh_n = b_hh[2 * HID + d];
  const float sc_r = scales[d] * (1.0f / 127.0f);
  const float sc_z = scales[HID + d] * (1.0f / 127.0f);
  const float sc_n = scales[2 * HID + d] * (1.0f / 127.0f);
  const half2_t wbx2 = half2_t{(_Float16)Wb_x[0], (_Float16)Wb_x[1]};  // uniform
  const float bbeta = b_beta[0];
  const unsigned wbq_l = wbq[lane];       // Wb_h i8, dims 4*lane..4*lane+3
  const float wbsc = wbscale[0];          // folded (amax/127)*(1/127)

  // ---- init ----
  if (tid < 128) reinterpret_cast<unsigned*>(hq)[tid] = 0u;
  if (tid < 4) red[tid] = 0.0f;
  float h_old = 0.0f, vr = 0.0f, vz = 0.0f, vn = 0.0f;
  float* betas = out + BATCH;
  const float2* xg2 = reinterpret_cast<const float2*>(x + (size_t)b * TLEN * 2);
  float2 xv;
  if (sub == 0) xv = xg2[0];
  __syncthreads();

  int cur = 0;
  for (int t = 0; t < TLEN; ++t) {
    // ---- phase 1a (lower): per-wave hWb from h_{t-1} (hides under burst) --
    int hwb_i = 0;
    if (sub == 0) {
      const unsigned hw_l = reinterpret_cast<const unsigned*>(hq[cur])[lane];
      hwb_i = SDOT4(hw_l, wbq_l, 0);
      hwb_i = wave_sum63_i(hwb_i);
    }

    // ---- phase 1b (all): half-k i8 matvec burst, 6 accumulators ----
    const int4* hb = reinterpret_cast<const int4*>(hq[cur]) + sub * 8;
    int ar0 = 0, az0 = 0, an0 = 0, ar1 = 0, az1 = 0, an1 = 0;
#pragma unroll
    for (int c = 0; c < 4; ++c) {
      const int4 h0 = hb[2 * c];
      const int4 h1 = hb[2 * c + 1];
      ar0 = SDOT4(h0.x, wr[2 * c].x, ar0);
      az0 = SDOT4(h0.x, wz[2 * c].x, az0);
      an0 = SDOT4(h0.x, wn[2 * c].x, an0);
      ar1 = SDOT4(h1.x, wr[2 * c + 1].x, ar1);
      az1 = SDOT4(h1.x, wz[2 * c + 1].x, az1);
      an1 = SDOT4(h1.x, wn[2 * c + 1].x, an1);
      ar0 = SDOT4(h0.y, wr[2 * c].y, ar0);
      az0 = SDOT4(h0.y, wz[2 * c].y, az0);
      an0 = SDOT4(h0.y, wn[2 * c].y, an0);
      ar1 = SDOT4(h1.y, wr[2 * c + 1].y, ar1);
      az1 = SDOT4(h1.y, wz[2 * c + 1].y, az1);
      an1 = SDOT4(h1.y, wn[2 * c + 1].y, an1);
      ar0 = SDOT4(h0.z, wr[2 * c].z, ar0);
      az0 = SDOT4(h0.z, wz[2 * c].z, az0);
      an0 = SDOT4(h0.z, wn[2 * c].z, an0);
      ar1 = SDOT4(h1.z, wr[2 * c + 1].z, ar1);
      az1 = SDOT4(h1.z, wz[2 * c + 1].z, az1);
      an1 = SDOT4(h1.z, wn[2 * c + 1].z, an1);
      ar0 = SDOT4(h0.w, wr[2 * c].w, ar0);
      az0 = SDOT4(h0.w, wz[2 * c].w, az0);
      an0 = SDOT4(h0.w, wn[2 * c].w, an0);
      ar1 = SDOT4(h1.w, wr[2 * c + 1].w, ar1);
      az1 = SDOT4(h1.w, wz[2 * c + 1].w, az1);
      an1 = SDOT4(h1.w, wn[2 * c + 1].w, an1);
    }
    const int ar = ar0 + ar1, az = az0 + az1, an = an0 + an1;

    float beta = 0.0f;
    if (sub == 1) {
      // ---- phase 1c (upper): publish partial sums ----
      parts[d] = ar;
      parts[HID + d] = az;
      parts[2 * HID + d] = an;
    } else {
      // ---- phase 1c (lower): beta + momentum (overlaps upper's writes) ----
      const float hWb = (float)__builtin_amdgcn_readlane(hwb_i, 63) * wbsc;
      const half2_t x2 = half2_t{(_Float16)xv.x, (_Float16)xv.y};
      xv = xg2[(t + 1 < TLEN) ? t + 1 : t];
      beta = fast_sigmoid(dot2acc(x2, wbx2, hWb + bbeta));
      vr = beta * vr + dot2acc(x2, wih_r, bih_r);
      vz = beta * vz + dot2acc(x2, wih_z, bih_z);
      vn = beta * vn + dot2acc(x2, wih_n, bih_n);
    }
    __syncthreads();

    // ---- phase 2 (lower only): combine partials, gates, h', quantize ----
    if (sub == 0) {
      const float r = fast_sigmoid(vr + (float)(ar + parts[d]) * sc_r + bhh_r);
      const float z = fast_sigmoid(vz + (float)(az + parts[HID + d]) * sc_z + bhh_z);
      const float n = fast_tanh(vn + r * ((float)(an + parts[2 * HID + d]) * sc_n + bhh_n));
      h_old = (1.0f - z) * n + z * h_old;
      const int qb = (int)rintf(h_old * 127.0f);
      reinterpret_cast<unsigned char*>(hq[cur ^ 1])[d] = (unsigned char)(qb & 0xff);
      if (tid == 0) betas[(size_t)b * TLEN + t] = beta;
    }
    __syncthreads();
    cur ^= 1;
  }

  // ---- head (h_T lives in lower threads) ----
  if (sub == 0) {
    float hp = h_old * W_head[d];
    hp = wave_sum63_f(hp);
    if (lane == 63) red[wv] = hp;
  }
  __syncthreads();
  if (tid == 0)
    out[b] = ((red[0] + red[1]) + (red[2] + red[3])) + b_head[0];
}

extern "C" void kernel_launch(void* const* d_in, const int* in_sizes, int n_in,
                              void* d_out, int out_size, void* d_ws, size_t ws_size,
                              hipStream_t stream) {
  const float* x      = (const float*)d_in[0];
  const float* W_ih   = (const float*)d_in[1];
  const float* W_hh   = (const float*)d_in[2];
  const float* b_ih   = (const float*)d_in[3];
  const float* b_hh   = (const float*)d_in[4];
  const float* Wb_x   = (const float*)d_in[5];
  const float* Wb_h   = (const float*)d_in[6];
  const float* b_beta = (const float*)d_in[7];
  const float* s      = (const float*)d_in[8];
  const float* W_head = (const float*)d_in[9];
  const float* b_head = (const float*)d_in[10];
  float* out = (float*)d_out;

  char* wsb = (char*)d_ws;
  uint4*    wq      = (uint4*)wsb;                 // 768*16*16 = 196608 B
  float*    scales  = (float*)(wsb + 196608);      // 768*4 = 3072 B
  unsigned* wbq     = (unsigned*)(wsb + 199680);   // 64*4 = 256 B
  float*    wbscale = (float*)(wsb + 199936);      // 4 B

  quant_whh<<<dim3(4), dim3(256), 0, stream>>>(W_hh, Wb_h, wq, scales, wbq, wbscale);
  momgru_persistent<<<dim3(BATCH), dim3(512), 0, stream>>>(
      x, W_ih, b_ih, b_hh, Wb_x, b_beta, s, W_head, b_head,
      (const uint4*)wq, (const float*)scales, (const unsigned*)wbq,
      (const float*)wbscale, out);
}